// Round 12
// baseline (399.239 us; speedup 1.0000x reference)
//
#include <hip/hip_runtime.h>
#include <math.h>

// Stage1: N=4096 -> np=128, r=0.02, ns=32, layers (9->32), (32->64)
// Stage2: N=128  -> np=64,  r=0.04, ns=32, layers (67->128), (128->128)
// Stage3: N=64   -> np=32,  r=0.08, ns=16, layers (131->256), (256->256)
//
// Factored MLPs: U1[p]=b2+W2feat·f1[p] (in group1), U2[p]=b4+W4feat·f2[p] (in group2).
//
// ws layout (floats):
//   wT [0,126848): L0@0(12x32) L1@384(32x64) L2@2432(68x128)
//                  L3@11136(128x128) L4@27520(132x256) L5@61312(256x256)
//   bias [126848,127712) offs 0,32,96,224,352,608
//   xyz1 131072  xyz2 155648  xyz3 167936
//   U1 174080 (64*128*128)  U2 1222656 (64*64*256)  end 2271232

struct PrepArgs {
  const float* w[6]; const float* g[6]; const float* be[6];
  const float* rm[6]; const float* rv[6];
};

__device__ __forceinline__ void prep_body(const PrepArgs& a, float* __restrict__ wT,
                                          float* __restrict__ bias, int i) {
  const int woff[7] = {0, 384, 2432, 11136, 27520, 61312, 126848};
  const int cin[6]  = {9, 32, 67, 128, 131, 256};
  const int osh[6]  = {5, 6, 7, 7, 8, 8};
  const int boff[7] = {0, 32, 96, 224, 352, 608, 864};
  if (i < 126848) {
    int l = 0;
    while (i >= woff[l + 1]) ++l;
    int local = i - woff[l];
    int c = local >> osh[l];
    int o = local & ((1 << osh[l]) - 1);
    float sc = a.g[l][o] / sqrtf(a.rv[l][o] + 1e-5f);
    wT[i] = (c < cin[l]) ? a.w[l][o * cin[l] + c] * sc : 0.f;
  } else if (i < 127712) {
    int j = i - 126848;
    int l = 0;
    while (j >= boff[l + 1]) ++l;
    int o = j - boff[l];
    float sc = a.g[l][o] / sqrtf(a.rv[l][o] + 1e-5f);
    bias[j] = a.be[l][o] - a.rm[l][o] * sc;
  }
}

__device__ __forceinline__ float dist2_exact(float px, float py, float pz,
                                             float cx, float cy, float cz) {
  float dx = px - cx, dy = py - cy, dz = pz - cz;
  return __fadd_rn(__fadd_rn(__fmul_rn(dx, dx), __fmul_rn(dy, dy)), __fmul_rn(dz, dz));
}

// DPP wave64 max of nonnegative values; full max lands in lane 63.
__device__ __forceinline__ float wave_max64_dpp(float v) {
  int x;
  x = __builtin_amdgcn_update_dpp(0, __float_as_int(v), 0x111, 0xf, 0xf, true);
  v = fmaxf(v, __int_as_float(x));
  x = __builtin_amdgcn_update_dpp(0, __float_as_int(v), 0x112, 0xf, 0xf, true);
  v = fmaxf(v, __int_as_float(x));
  x = __builtin_amdgcn_update_dpp(0, __float_as_int(v), 0x114, 0xf, 0xf, true);
  v = fmaxf(v, __int_as_float(x));
  x = __builtin_amdgcn_update_dpp(0, __float_as_int(v), 0x118, 0xf, 0xf, true);
  v = fmaxf(v, __int_as_float(x));
  x = __builtin_amdgcn_update_dpp(0, __float_as_int(v), 0x142, 0xa, 0xf, true);
  v = fmaxf(v, __int_as_float(x));
  x = __builtin_amdgcn_update_dpp(0, __float_as_int(v), 0x143, 0xc, 0xf, true);
  v = fmaxf(v, __int_as_float(x));
  return v;
}
__device__ __forceinline__ float rl_f(float v, int lane) {
  return __int_as_float(__builtin_amdgcn_readlane(__float_as_int(v), lane));
}

// ---------------- FPS stage 1 (+ fused weight prep): 256 threads -------------
// 4 waves, 16 pts/thread in regs (VGPRs free: 64 blocks on 256 CUs),
// coord-carrying candidates, 4-row combine, one barrier/iter.
__global__ __launch_bounds__(256) void fps1_prep_kernel(const float* __restrict__ pc,
    float* __restrict__ newxyz, PrepArgs pa, float* __restrict__ wT,
    float* __restrict__ bias) {
  int t = threadIdx.x;
  if (blockIdx.x >= 64) {
    prep_body(pa, wT, bias, (int)(blockIdx.x - 64) * 256 + t);
    return;
  }
  int b = blockIdx.x;
  const float* xb = pc + (size_t)b * 4096 * 3;
  float* out = newxyz + (size_t)b * 128 * 3;
  __shared__ float candf[2][4][4];  // [parity][wave][v,x,y,z]
  __shared__ float out_lds[128 * 3];
  float px[16], py[16], pz[16], dist[16];
  {
    float fl[48];
    const float4* xb4 = reinterpret_cast<const float4*>(xb + t * 48);
    #pragma unroll
    for (int u = 0; u < 12; ++u) {
      float4 L = xb4[u];
      fl[4 * u] = L.x; fl[4 * u + 1] = L.y; fl[4 * u + 2] = L.z; fl[4 * u + 3] = L.w;
    }
    #pragma unroll
    for (int k = 0; k < 16; ++k) {
      px[k] = fl[3 * k]; py[k] = fl[3 * k + 1]; pz[k] = fl[3 * k + 2];
      dist[k] = 1e10f;
    }
  }
  float cx = xb[0], cy = xb[1], cz = xb[2];
  if (t == 0) { out_lds[0] = cx; out_lds[1] = cy; out_lds[2] = cz; }
  int lane = t & 63, wv = t >> 6;
  for (int it = 1; it < 128; ++it) {
    float bv = -1.f, bx = px[0], by = py[0], bz = pz[0];
    #pragma unroll
    for (int k = 0; k < 16; ++k) {
      float d = dist2_exact(px[k], py[k], pz[k], cx, cy, cz);
      float nd = fminf(dist[k], d);
      dist[k] = nd;
      bool up = nd > bv;               // strict > keeps smallest k (ascending idx)
      bv = up ? nd : bv;
      bx = up ? px[k] : bx; by = up ? py[k] : by; bz = up ? pz[k] : bz;
    }
    float wm = rl_f(wave_max64_dpp(bv), 63);
    unsigned long long m = __ballot(bv == wm);
    int src = __ffsll(m) - 1;          // smallest lane == smallest point index
    int pb = it & 1;
    if (lane == src) {
      candf[pb][wv][0] = bv; candf[pb][wv][1] = bx;
      candf[pb][wv][2] = by; candf[pb][wv][3] = bz;
    }
    __syncthreads();
    float4 bc = *reinterpret_cast<const float4*>(&candf[pb][0][0]);
    #pragma unroll
    for (int w = 1; w < 4; ++w) {
      float4 cw = *reinterpret_cast<const float4*>(&candf[pb][w][0]);
      bool up = cw.x > bc.x;           // tie -> keep earlier wave (smaller idx)
      bc.x = up ? cw.x : bc.x; bc.y = up ? cw.y : bc.y;
      bc.z = up ? cw.z : bc.z; bc.w = up ? cw.w : bc.w;
    }
    cx = bc.y; cy = bc.z; cz = bc.w;
    if (t == 0) { out_lds[it * 3] = cx; out_lds[it * 3 + 1] = cy; out_lds[it * 3 + 2] = cz; }
  }
  __syncthreads();
  for (int e = t; e < 384; e += 256) out[e] = out_lds[e];
}

// ---------------- FPS stage 2/3 bodies ----------------
__device__ __forceinline__ void fps2_body(const float* __restrict__ xyz1,
                                          float* __restrict__ out_xyz, int b, int t) {
  const float* xb = xyz1 + (size_t)b * 128 * 3;
  float* out = out_xyz + (size_t)b * 64 * 3;
  float px[2], py[2], pz[2], dist[2];
  #pragma unroll
  for (int k = 0; k < 2; ++k) {
    int i = t * 2 + k;
    px[k] = xb[i * 3]; py[k] = xb[i * 3 + 1]; pz[k] = xb[i * 3 + 2];
    dist[k] = 1e10f;
  }
  float cx = rl_f(px[0], 0), cy = rl_f(py[0], 0), cz = rl_f(pz[0], 0);
  if (t == 0) { out[0] = cx; out[1] = cy; out[2] = cz; }
  for (int it = 1; it < 64; ++it) {
    float bv = -1.f; int lidx = t * 2;
    #pragma unroll
    for (int k = 0; k < 2; ++k) {
      float d = dist2_exact(px[k], py[k], pz[k], cx, cy, cz);
      float nd = fminf(dist[k], d);
      dist[k] = nd;
      if (nd > bv) { bv = nd; lidx = t * 2 + k; }
    }
    float wm = rl_f(wave_max64_dpp(bv), 63);
    unsigned long long m = __ballot(bv == wm);
    int src = __ffsll(m) - 1;
    int widx = __builtin_amdgcn_readlane(lidx, src);
    int sl = widx >> 1, sk = widx & 1;
    float qx = sk ? px[1] : px[0], qy = sk ? py[1] : py[0], qz = sk ? pz[1] : pz[0];
    cx = rl_f(qx, sl); cy = rl_f(qy, sl); cz = rl_f(qz, sl);
    if (t == 0) { out[it * 3] = cx; out[it * 3 + 1] = cy; out[it * 3 + 2] = cz; }
  }
}

__device__ __forceinline__ void fps3_body(const float* __restrict__ xyz2,
                                          float* __restrict__ out_xyz, int b, int t) {
  const float* xb = xyz2 + (size_t)b * 64 * 3;
  float* out = out_xyz + (size_t)b * 32 * 3;
  float px = xb[t * 3], py = xb[t * 3 + 1], pz = xb[t * 3 + 2];
  float dist = 1e10f;
  float cx = rl_f(px, 0), cy = rl_f(py, 0), cz = rl_f(pz, 0);
  if (t == 0) { out[0] = cx; out[1] = cy; out[2] = cz; }
  for (int it = 1; it < 32; ++it) {
    float d = dist2_exact(px, py, pz, cx, cy, cz);
    dist = fminf(dist, d);
    float wm = rl_f(wave_max64_dpp(dist), 63);
    unsigned long long m = __ballot(dist == wm);
    int widx = __ffsll(m) - 1;
    cx = rl_f(px, widx); cy = rl_f(py, widx); cz = rl_f(pz, widx);
    if (t == 0) { out[it * 3] = cx; out[it * 3 + 1] = cy; out[it * 3 + 2] = cz; }
  }
}

// ---------------- ball query (single wave) ----------------
__device__ __forceinline__ int ball_query_wave(const float* __restrict__ xb, int N,
                                               float cx, float cy, float cz, float r2,
                                               int nsample, int* list, int lane) {
  int cnt = 0;
  for (int base = 0; base < N && cnt < nsample; base += 64) {
    int i = base + lane;
    float d2 = dist2_exact(xb[i * 3], xb[i * 3 + 1], xb[i * 3 + 2], cx, cy, cz);
    bool in = d2 < r2;
    unsigned long long m = __ballot(in);
    if (in) {
      int pos = cnt + __popcll(m & ((1ull << lane) - 1ull));
      if (pos < nsample) list[pos] = i;
    }
    cnt += __popcll(m);
  }
  return cnt;
}

// software-pipelined variant for large N.
__device__ __forceinline__ int ball_query_wave_pf(const float* __restrict__ xb, int N,
                                                  float cx, float cy, float cz, float r2,
                                                  int nsample, int* list, int lane) {
  int cnt = 0;
  float x = xb[lane * 3], y = xb[lane * 3 + 1], z = xb[lane * 3 + 2];
  for (int base = 0; base < N && cnt < nsample; base += 64) {
    float nx = x, ny = y, nz = z;
    if (base + 64 < N) {
      int ni = base + 64 + lane;
      nx = xb[ni * 3]; ny = xb[ni * 3 + 1]; nz = xb[ni * 3 + 2];
    }
    float d2 = dist2_exact(x, y, z, cx, cy, cz);
    bool in = d2 < r2;
    unsigned long long m = __ballot(in);
    if (in) {
      int pos = cnt + __popcll(m & ((1ull << lane) - 1ull));
      if (pos < nsample) list[pos] = base + lane;
    }
    cnt += __popcll(m);
    x = nx; y = ny; z = nz;
  }
  return cnt;
}

#define FMA4(aq, w0, w1, w2, w3, xv, comp)                                   \
  aq = fmaf(w0.comp, xv.x, fmaf(w1.comp, xv.y, fmaf(w2.comp, xv.z,           \
       fmaf(w3.comp, xv.w, aq))))

// ---------------- group1 (+fps2): 4 groups/block, 128 j, grid (33,64) --------
__global__ __launch_bounds__(256) void group1_fps2_kernel(const float* __restrict__ pc,
    const float* __restrict__ newxyz1, const float* __restrict__ wbuf,
    const float* __restrict__ bbuf, float* __restrict__ U1,
    float* __restrict__ xyz2) {
  int t = threadIdx.x;
  int b = blockIdx.y;
  if (blockIdx.x == 32) {
    if (t < 64) fps2_body(newxyz1, xyz2, b, t);
    return;
  }
  __shared__ float smA[1536];      // X [128][12]  /  pm1 [16][64] (aliased)
  __shared__ float h1[128 * 36];
  __shared__ float W0s[384];
  __shared__ float W1s[2048];
  __shared__ float F1[4 * 64];
  __shared__ float ctr[12];
  __shared__ int lst[128];         // [4][32]
  __shared__ int cnts[4];
  float* X = smA;
  float* pm1 = smA;
  int s0 = blockIdx.x * 4;
  const float* xb = pc + (size_t)b * 4096 * 3;
  const float* W2g = wbuf + 2432;
  for (int e = t; e < 384; e += 256) W0s[e] = wbuf[e];
  for (int e = t; e < 2048; e += 256) W1s[e] = wbuf[384 + e];
  int lane = t & 63, wv = t >> 6;
  {
    int g = wv;
    const float* c3 = newxyz1 + ((size_t)b * 128 + s0 + g) * 3;
    float cx = c3[0], cy = c3[1], cz = c3[2];
    if (lane == 0) { ctr[g * 3] = cx; ctr[g * 3 + 1] = cy; ctr[g * 3 + 2] = cz; }
    int cnt = ball_query_wave_pf(xb, 4096, cx, cy, cz, 4.0e-4f, 32, lst + g * 32, lane);
    if (lane == 0) cnts[g] = cnt;
  }
  __syncthreads();
  if (t < 128) { int g = t >> 5, q = t & 31; if (q >= cnts[g]) lst[t] = (cnts[g] > 0) ? lst[g * 32] : 0; }
  __syncthreads();
  if (t < 128) {
    int j = t;
    int g = j >> 5;
    int i = lst[g * 32 + (j & 31)];
    float px = xb[i * 3], py = xb[i * 3 + 1], pz = xb[i * 3 + 2];
    float4 v0, v1, v2;
    v0.x = px - ctr[g * 3]; v0.y = py - ctr[g * 3 + 1]; v0.z = pz - ctr[g * 3 + 2];
    v0.w = px; v1.x = py; v1.y = pz; v1.z = px; v1.w = py;
    v2.x = pz; v2.y = 0.f; v2.z = 0.f; v2.w = 0.f;
    *reinterpret_cast<float4*>(&X[j * 12 + 0]) = v0;
    *reinterpret_cast<float4*>(&X[j * 12 + 4]) = v1;
    *reinterpret_cast<float4*>(&X[j * 12 + 8]) = v2;
  }
  __syncthreads();
  {
    int o_l0 = t & 31, jb0 = (t >> 5) * 16;
    float w0v[12];
    #pragma unroll
    for (int c = 0; c < 12; ++c) w0v[c] = W0s[c * 32 + o_l0];
    float b0 = bbuf[o_l0];
    for (int jj = 0; jj < 16; ++jj) {
      int j = jb0 + jj;
      float4 x0 = *reinterpret_cast<const float4*>(&X[j * 12 + 0]);
      float4 x1 = *reinterpret_cast<const float4*>(&X[j * 12 + 4]);
      float4 x2 = *reinterpret_cast<const float4*>(&X[j * 12 + 8]);
      float a = b0;
      a = fmaf(w0v[0], x0.x, a); a = fmaf(w0v[1], x0.y, a);
      a = fmaf(w0v[2], x0.z, a); a = fmaf(w0v[3], x0.w, a);
      a = fmaf(w0v[4], x1.x, a); a = fmaf(w0v[5], x1.y, a);
      a = fmaf(w0v[6], x1.z, a); a = fmaf(w0v[7], x1.w, a);
      a = fmaf(w0v[8], x2.x, a); a = fmaf(w0v[9], x2.y, a);
      a = fmaf(w0v[10], x2.z, a); a = fmaf(w0v[11], x2.w, a);
      h1[j * 36 + o_l0] = fmaxf(a, 0.f);
    }
  }
  __syncthreads();
  {
    int ot1 = t & 15, jt1 = t >> 4;
    int o0 = ot1 * 4, j0 = jt1 * 8;
    float acc[8][4];
    #pragma unroll
    for (int q = 0; q < 8; ++q)
      #pragma unroll
      for (int r = 0; r < 4; ++r) acc[q][r] = bbuf[32 + o0 + r];
    #pragma unroll 2
    for (int c4 = 0; c4 < 8; ++c4) {
      int c = c4 * 4;
      float4 w0 = *reinterpret_cast<const float4*>(&W1s[(c + 0) * 64 + o0]);
      float4 w1 = *reinterpret_cast<const float4*>(&W1s[(c + 1) * 64 + o0]);
      float4 w2 = *reinterpret_cast<const float4*>(&W1s[(c + 2) * 64 + o0]);
      float4 w3 = *reinterpret_cast<const float4*>(&W1s[(c + 3) * 64 + o0]);
      #pragma unroll
      for (int q = 0; q < 8; ++q) {
        float4 xv = *reinterpret_cast<const float4*>(&h1[(j0 + q) * 36 + c]);
        FMA4(acc[q][0], w0, w1, w2, w3, xv, x);
        FMA4(acc[q][1], w0, w1, w2, w3, xv, y);
        FMA4(acc[q][2], w0, w1, w2, w3, xv, z);
        FMA4(acc[q][3], w0, w1, w2, w3, xv, w);
      }
    }
    float m[4] = {-1e30f, -1e30f, -1e30f, -1e30f};
    #pragma unroll
    for (int q = 0; q < 8; ++q)
      #pragma unroll
      for (int r = 0; r < 4; ++r) m[r] = fmaxf(m[r], acc[q][r]);
    float4 mv; mv.x = m[0]; mv.y = m[1]; mv.z = m[2]; mv.w = m[3];
    *reinterpret_cast<float4*>(&pm1[jt1 * 64 + o0]) = mv;
  }
  __syncthreads();
  {
    int o = t & 63, g = t >> 6;
    float v = pm1[(4 * g + 0) * 64 + o];
    v = fmaxf(v, pm1[(4 * g + 1) * 64 + o]);
    v = fmaxf(v, pm1[(4 * g + 2) * 64 + o]);
    v = fmaxf(v, pm1[(4 * g + 3) * 64 + o]);
    F1[g * 64 + o] = fmaxf(v, 0.f);
  }
  __syncthreads();
  {
    int o = t & 127, ph = t >> 7;
    float a0 = bbuf[96 + o], a1 = a0;
    #pragma unroll 8
    for (int c = 0; c < 64; ++c) {
      float w = W2g[(3 + c) * 128 + o];
      a0 = fmaf(w, F1[ph * 64 + c], a0);
      a1 = fmaf(w, F1[(ph + 2) * 64 + c], a1);
    }
    U1[((size_t)b * 128 + s0 + ph) * 128 + o] = a0;
    U1[((size_t)b * 128 + s0 + ph + 2) * 128 + o] = a1;
  }
}

// ---------------- group2 (+fps3): 2 groups/block, 64 j, grid (33,64) ---------
__global__ __launch_bounds__(256) void group2_fps3_kernel(const float* __restrict__ xyz1,
    const float* __restrict__ newxyz2, const float* __restrict__ U1,
    const float* __restrict__ wbuf, const float* __restrict__ bbuf,
    float* __restrict__ U2, float* __restrict__ xyz3) {
  int t = threadIdx.x;
  int b = blockIdx.y;
  if (blockIdx.x == 32) {
    if (t < 64) fps3_body(newxyz2, xyz3, b, t);
    return;
  }
  __shared__ float Hs[64 * 132];   // front 1024 floats reused as pm [8][128]
  __shared__ float W2x[384];
  __shared__ float D[64 * 4];
  __shared__ float F2[2 * 128];
  __shared__ float ctr[6];
  __shared__ int lst[64];          // [2][32]
  __shared__ int cnts[2];
  float* pm = Hs;
  int s0 = blockIdx.x * 2;
  const float* xb = xyz1 + (size_t)b * 128 * 3;
  const float* W2g = wbuf + 2432;
  const float* W3g = wbuf + 11136;
  const float* W4g = wbuf + 27520;
  int lane = t & 63, wv = t >> 6;
  for (int e = t; e < 384; e += 256) W2x[e] = W2g[e];
  if (wv < 2) {
    int g = wv;
    const float* c3 = newxyz2 + ((size_t)b * 64 + s0 + g) * 3;
    float cx = c3[0], cy = c3[1], cz = c3[2];
    if (lane == 0) { ctr[g * 3] = cx; ctr[g * 3 + 1] = cy; ctr[g * 3 + 2] = cz; }
    int cnt = ball_query_wave(xb, 128, cx, cy, cz, 1.6e-3f, 32, lst + g * 32, lane);
    if (lane == 0) cnts[g] = cnt;
  }
  __syncthreads();
  if (t < 64) { int g = t >> 5, q = t & 31; if (q >= cnts[g]) lst[t] = (cnts[g] > 0) ? lst[g * 32] : 0; }
  __syncthreads();
  int ot = t & 31, jt = t >> 5;
  int o0 = ot * 4, j0 = jt * 8;
  float4 wx0 = *reinterpret_cast<const float4*>(&W2x[0 * 128 + o0]);
  float4 wx1 = *reinterpret_cast<const float4*>(&W2x[1 * 128 + o0]);
  float4 wx2 = *reinterpret_cast<const float4*>(&W2x[2 * 128 + o0]);
  if (t < 64) {
    int j = t;
    int g = j >> 5;
    int i = lst[g * 32 + (j & 31)];
    D[j * 4 + 0] = xb[i * 3 + 0] - ctr[g * 3 + 0];
    D[j * 4 + 1] = xb[i * 3 + 1] - ctr[g * 3 + 1];
    D[j * 4 + 2] = xb[i * 3 + 2] - ctr[g * 3 + 2];
    D[j * 4 + 3] = 0.f;
  }
  __syncthreads();
  #pragma unroll
  for (int q = 0; q < 8; ++q) {
    int j = j0 + q;
    int g = j >> 5;
    int i = lst[g * 32 + (j & 31)];
    float4 u = *reinterpret_cast<const float4*>(&U1[((size_t)b * 128 + i) * 128 + o0]);
    float dx = D[j * 4], dy = D[j * 4 + 1], dz = D[j * 4 + 2];
    float4 h;
    h.x = fmaf(wx0.x, dx, fmaf(wx1.x, dy, fmaf(wx2.x, dz, u.x)));
    h.y = fmaf(wx0.y, dx, fmaf(wx1.y, dy, fmaf(wx2.y, dz, u.y)));
    h.z = fmaf(wx0.z, dx, fmaf(wx1.z, dy, fmaf(wx2.z, dz, u.z)));
    h.w = fmaf(wx0.w, dx, fmaf(wx1.w, dy, fmaf(wx2.w, dz, u.w)));
    h.x = fmaxf(h.x, 0.f); h.y = fmaxf(h.y, 0.f);
    h.z = fmaxf(h.z, 0.f); h.w = fmaxf(h.w, 0.f);
    *reinterpret_cast<float4*>(&Hs[j * 132 + o0]) = h;
  }
  __syncthreads();
  float acc[8][4];
  #pragma unroll
  for (int q = 0; q < 8; ++q)
    #pragma unroll
    for (int r = 0; r < 4; ++r) acc[q][r] = bbuf[224 + o0 + r];
  #pragma unroll 2
  for (int c4 = 0; c4 < 32; ++c4) {
    int c = c4 * 4;
    float4 w0 = *reinterpret_cast<const float4*>(&W3g[(c + 0) * 128 + o0]);
    float4 w1 = *reinterpret_cast<const float4*>(&W3g[(c + 1) * 128 + o0]);
    float4 w2 = *reinterpret_cast<const float4*>(&W3g[(c + 2) * 128 + o0]);
    float4 w3 = *reinterpret_cast<const float4*>(&W3g[(c + 3) * 128 + o0]);
    #pragma unroll
    for (int q = 0; q < 8; ++q) {
      float4 xv = *reinterpret_cast<const float4*>(&Hs[(j0 + q) * 132 + c]);
      FMA4(acc[q][0], w0, w1, w2, w3, xv, x);
      FMA4(acc[q][1], w0, w1, w2, w3, xv, y);
      FMA4(acc[q][2], w0, w1, w2, w3, xv, z);
      FMA4(acc[q][3], w0, w1, w2, w3, xv, w);
    }
  }
  __syncthreads();
  {
    float m[4] = {-1e30f, -1e30f, -1e30f, -1e30f};
    #pragma unroll
    for (int q = 0; q < 8; ++q)
      #pragma unroll
      for (int r = 0; r < 4; ++r) m[r] = fmaxf(m[r], acc[q][r]);
    float4 mv; mv.x = m[0]; mv.y = m[1]; mv.z = m[2]; mv.w = m[3];
    *reinterpret_cast<float4*>(&pm[jt * 128 + o0]) = mv;
  }
  __syncthreads();
  {
    int o = t & 127, g = t >> 7;
    float v = pm[(g * 4 + 0) * 128 + o];
    v = fmaxf(v, pm[(g * 4 + 1) * 128 + o]);
    v = fmaxf(v, pm[(g * 4 + 2) * 128 + o]);
    v = fmaxf(v, pm[(g * 4 + 3) * 128 + o]);
    F2[g * 128 + o] = fmaxf(v, 0.f);
  }
  __syncthreads();
  {
    int o = t;
    float a0 = bbuf[352 + o], a1 = a0;
    #pragma unroll 4
    for (int c = 0; c < 128; ++c) {
      float w = W4g[(3 + c) * 256 + o];
      a0 = fmaf(w, F2[c], a0);
      a1 = fmaf(w, F2[128 + c], a1);
    }
    U2[((size_t)b * 64 + s0) * 256 + o] = a0;
    U2[((size_t)b * 64 + s0 + 1) * 256 + o] = a1;
  }
}

// ---------------- group3: 2 groups/block, 32 j, grid (16,64) -----------------
__global__ __launch_bounds__(256) void group3_kernel(const float* __restrict__ xyz2,
    const float* __restrict__ newxyz3, const float* __restrict__ U2,
    const float* __restrict__ wbuf, const float* __restrict__ bbuf,
    float* __restrict__ out) {
  __shared__ float Hs3[32 * 260];  // front 1024 floats reused as pm3 [4][256]
  __shared__ float W4x[768];
  __shared__ float D[32 * 4];
  __shared__ float ctr[6];
  __shared__ int lst[32];          // [2][16]
  __shared__ int cnts[2];
  float* pm3 = Hs3;
  int t = threadIdx.x;
  int b = blockIdx.y, s0 = blockIdx.x * 2;
  const float* xb = xyz2 + (size_t)b * 64 * 3;
  const float* W4g = wbuf + 27520;
  const float* W5g = wbuf + 61312;
  int lane = t & 63, wv = t >> 6;
  for (int e = t; e < 768; e += 256) W4x[e] = W4g[e];
  if (wv < 2) {
    int g = wv;
    const float* c3 = newxyz3 + ((size_t)b * 32 + s0 + g) * 3;
    float cx = c3[0], cy = c3[1], cz = c3[2];
    if (lane == 0) { ctr[g * 3] = cx; ctr[g * 3 + 1] = cy; ctr[g * 3 + 2] = cz; }
    int cnt = ball_query_wave(xb, 64, cx, cy, cz, 6.4e-3f, 16, lst + g * 16, lane);
    if (lane == 0) cnts[g] = cnt;
  }
  __syncthreads();
  if (t < 32) { int g = t >> 4, q = t & 15; if (q >= cnts[g]) lst[t] = (cnts[g] > 0) ? lst[g * 16] : 0; }
  __syncthreads();
  int ot = t & 63, jt = t >> 6;
  int o0 = ot * 4, j0 = jt * 8;
  float4 wx0 = *reinterpret_cast<const float4*>(&W4x[0 * 256 + o0]);
  float4 wx1 = *reinterpret_cast<const float4*>(&W4x[1 * 256 + o0]);
  float4 wx2 = *reinterpret_cast<const float4*>(&W4x[2 * 256 + o0]);
  if (t < 32) {
    int j = t;
    int g = j >> 4;
    int i = lst[g * 16 + (j & 15)];
    D[j * 4 + 0] = xb[i * 3 + 0] - ctr[g * 3 + 0];
    D[j * 4 + 1] = xb[i * 3 + 1] - ctr[g * 3 + 1];
    D[j * 4 + 2] = xb[i * 3 + 2] - ctr[g * 3 + 2];
    D[j * 4 + 3] = 0.f;
  }
  __syncthreads();
  #pragma unroll
  for (int q = 0; q < 8; ++q) {
    int j = j0 + q;
    int g = j >> 4;
    int i = lst[g * 16 + (j & 15)];
    float4 u = *reinterpret_cast<const float4*>(&U2[((size_t)b * 64 + i) * 256 + o0]);
    float dx = D[j * 4], dy = D[j * 4 + 1], dz = D[j * 4 + 2];
    float4 h;
    h.x = fmaf(wx0.x, dx, fmaf(wx1.x, dy, fmaf(wx2.x, dz, u.x)));
    h.y = fmaf(wx0.y, dx, fmaf(wx1.y, dy, fmaf(wx2.y, dz, u.y)));
    h.z = fmaf(wx0.z, dx, fmaf(wx1.z, dy, fmaf(wx2.z, dz, u.z)));
    h.w = fmaf(wx0.w, dx, fmaf(wx1.w, dy, fmaf(wx2.w, dz, u.w)));
    h.x = fmaxf(h.x, 0.f); h.y = fmaxf(h.y, 0.f);
    h.z = fmaxf(h.z, 0.f); h.w = fmaxf(h.w, 0.f);
    *reinterpret_cast<float4*>(&Hs3[j * 260 + o0]) = h;
  }
  __syncthreads();
  float acc[8][4];
  #pragma unroll
  for (int q = 0; q < 8; ++q)
    #pragma unroll
    for (int r = 0; r < 4; ++r) acc[q][r] = bbuf[608 + o0 + r];
  #pragma unroll 2
  for (int c4 = 0; c4 < 64; ++c4) {
    int c = c4 * 4;
    float4 w0 = *reinterpret_cast<const float4*>(&W5g[(c + 0) * 256 + o0]);
    float4 w1 = *reinterpret_cast<const float4*>(&W5g[(c + 1) * 256 + o0]);
    float4 w2 = *reinterpret_cast<const float4*>(&W5g[(c + 2) * 256 + o0]);
    float4 w3 = *reinterpret_cast<const float4*>(&W5g[(c + 3) * 256 + o0]);
    #pragma unroll
    for (int q = 0; q < 8; ++q) {
      float4 xv = *reinterpret_cast<const float4*>(&Hs3[(j0 + q) * 260 + c]);
      FMA4(acc[q][0], w0, w1, w2, w3, xv, x);
      FMA4(acc[q][1], w0, w1, w2, w3, xv, y);
      FMA4(acc[q][2], w0, w1, w2, w3, xv, z);
      FMA4(acc[q][3], w0, w1, w2, w3, xv, w);
    }
  }
  __syncthreads();
  {
    float m[4] = {-1e30f, -1e30f, -1e30f, -1e30f};
    #pragma unroll
    for (int q = 0; q < 8; ++q)
      #pragma unroll
      for (int r = 0; r < 4; ++r) m[r] = fmaxf(m[r], acc[q][r]);
    float4 mv; mv.x = m[0]; mv.y = m[1]; mv.z = m[2]; mv.w = m[3];
    *reinterpret_cast<float4*>(&pm3[jt * 256 + o0]) = mv;
  }
  __syncthreads();
  {
    int o = t;
    #pragma unroll
    for (int g = 0; g < 2; ++g) {
      float v = fmaxf(pm3[(g * 2 + 0) * 256 + o], pm3[(g * 2 + 1) * 256 + o]);
      out[((size_t)b * 256 + o) * 32 + s0 + g] = fmaxf(v, 0.f);
    }
  }
}

extern "C" void kernel_launch(void* const* d_in, const int* in_sizes, int n_in,
                              void* d_out, int out_size, void* d_ws, size_t ws_size,
                              hipStream_t stream) {
  (void)in_sizes; (void)n_in; (void)out_size; (void)ws_size;
  const float* pc = (const float*)d_in[0];
  PrepArgs pa;
  for (int l = 0; l < 6; ++l) {
    pa.w[l]  = (const float*)d_in[1 + 5 * l + 0];
    pa.g[l]  = (const float*)d_in[1 + 5 * l + 1];
    pa.be[l] = (const float*)d_in[1 + 5 * l + 2];
    pa.rm[l] = (const float*)d_in[1 + 5 * l + 3];
    pa.rv[l] = (const float*)d_in[1 + 5 * l + 4];
  }
  float* ws = (float*)d_ws;
  float* wbuf = ws + 0;
  float* bbuf = ws + 126848;
  float* xyz1 = ws + 131072;
  float* xyz2 = ws + 155648;
  float* xyz3 = ws + 167936;
  float* U1   = ws + 174080;    // 64*128*128 floats
  float* U2   = ws + 1222656;   // 64*64*256 floats
  float* out  = (float*)d_out;

  fps1_prep_kernel<<<563, 256, 0, stream>>>(pc, xyz1, pa, wbuf, bbuf);
  group1_fps2_kernel<<<dim3(33, 64), 256, 0, stream>>>(pc, xyz1, wbuf, bbuf, U1, xyz2);
  group2_fps3_kernel<<<dim3(33, 64), 256, 0, stream>>>(xyz1, xyz2, U1, wbuf, bbuf, U2, xyz3);
  group3_kernel<<<dim3(16, 64), 256, 0, stream>>>(xyz2, xyz3, U2, wbuf, bbuf, out);
}

// Round 13
// 380.139 us; speedup vs baseline: 1.0502x; 1.0502x over previous
//
#include <hip/hip_runtime.h>
#include <math.h>

// Stage1: N=4096 -> np=128, r=0.02, ns=32, layers (9->32), (32->64)
// Stage2: N=128  -> np=64,  r=0.04, ns=32, layers (67->128), (128->128)
// Stage3: N=64   -> np=32,  r=0.08, ns=16, layers (131->256), (256->256)
//
// Factored MLPs: U1[p]=b2+W2feat·f1[p] (in group1), U2[p]=b4+W4feat·f2[p] (in group2).
//
// ws layout (floats):
//   wT [0,126848): L0@0(12x32) L1@384(32x64) L2@2432(68x128)
//                  L3@11136(128x128) L4@27520(132x256) L5@61312(256x256)
//   bias [126848,127712) offs 0,32,96,224,352,608
//   xyz1 131072  xyz2 155648  xyz3 167936
//   U1 174080 (64*128*128)  U2 1222656 (64*64*256)  end 2271232

struct PrepArgs {
  const float* w[6]; const float* g[6]; const float* be[6];
  const float* rm[6]; const float* rv[6];
};

__device__ __forceinline__ void prep_body(const PrepArgs& a, float* __restrict__ wT,
                                          float* __restrict__ bias, int i) {
  const int woff[7] = {0, 384, 2432, 11136, 27520, 61312, 126848};
  const int cin[6]  = {9, 32, 67, 128, 131, 256};
  const int osh[6]  = {5, 6, 7, 7, 8, 8};
  const int boff[7] = {0, 32, 96, 224, 352, 608, 864};
  if (i < 126848) {
    int l = 0;
    while (i >= woff[l + 1]) ++l;
    int local = i - woff[l];
    int c = local >> osh[l];
    int o = local & ((1 << osh[l]) - 1);
    float sc = a.g[l][o] / sqrtf(a.rv[l][o] + 1e-5f);
    wT[i] = (c < cin[l]) ? a.w[l][o * cin[l] + c] * sc : 0.f;
  } else if (i < 127712) {
    int j = i - 126848;
    int l = 0;
    while (j >= boff[l + 1]) ++l;
    int o = j - boff[l];
    float sc = a.g[l][o] / sqrtf(a.rv[l][o] + 1e-5f);
    bias[j] = a.be[l][o] - a.rm[l][o] * sc;
  }
}

__device__ __forceinline__ float dist2_exact(float px, float py, float pz,
                                             float cx, float cy, float cz) {
  float dx = px - cx, dy = py - cy, dz = pz - cz;
  return __fadd_rn(__fadd_rn(__fmul_rn(dx, dx), __fmul_rn(dy, dy)), __fmul_rn(dz, dz));
}

// DPP wave64 max of nonnegative values; full max lands in lane 63.
__device__ __forceinline__ float wave_max64_dpp(float v) {
  int x;
  x = __builtin_amdgcn_update_dpp(0, __float_as_int(v), 0x111, 0xf, 0xf, true);
  v = fmaxf(v, __int_as_float(x));
  x = __builtin_amdgcn_update_dpp(0, __float_as_int(v), 0x112, 0xf, 0xf, true);
  v = fmaxf(v, __int_as_float(x));
  x = __builtin_amdgcn_update_dpp(0, __float_as_int(v), 0x114, 0xf, 0xf, true);
  v = fmaxf(v, __int_as_float(x));
  x = __builtin_amdgcn_update_dpp(0, __float_as_int(v), 0x118, 0xf, 0xf, true);
  v = fmaxf(v, __int_as_float(x));
  x = __builtin_amdgcn_update_dpp(0, __float_as_int(v), 0x142, 0xa, 0xf, true);
  v = fmaxf(v, __int_as_float(x));
  x = __builtin_amdgcn_update_dpp(0, __float_as_int(v), 0x143, 0xc, 0xf, true);
  v = fmaxf(v, __int_as_float(x));
  return v;
}
__device__ __forceinline__ float rl_f(float v, int lane) {
  return __int_as_float(__builtin_amdgcn_readlane(__float_as_int(v), lane));
}

// pairwise candidate combine keeping lower index on ties (strict > on hi operand)
__device__ __forceinline__ float4 cand_max(float4 lo, float4 hi) {
  bool up = hi.x > lo.x;
  float4 r;
  r.x = up ? hi.x : lo.x; r.y = up ? hi.y : lo.y;
  r.z = up ? hi.z : lo.z; r.w = up ? hi.w : lo.w;
  return r;
}

// ---------------- FPS stage 1 (+ fused weight prep): 512 threads -------------
// R9/R11-proven: 8 pts/thread in regs, coord-carrying candidates, one
// barrier/iter; block combine via 3-level tree (first-index-wins preserved).
__global__ __launch_bounds__(512) void fps1_prep_kernel(const float* __restrict__ pc,
    float* __restrict__ newxyz, PrepArgs pa, float* __restrict__ wT,
    float* __restrict__ bias) {
  int t = threadIdx.x;
  if (blockIdx.x >= 64) {
    prep_body(pa, wT, bias, (int)(blockIdx.x - 64) * 512 + t);
    return;
  }
  int b = blockIdx.x;
  const float* xb = pc + (size_t)b * 4096 * 3;
  float* out = newxyz + (size_t)b * 128 * 3;
  __shared__ float candf[2][8][4];
  __shared__ float out_lds[128 * 3];
  float px[8], py[8], pz[8], dist[8];
  {
    float fl[24];
    const float4* xb4 = reinterpret_cast<const float4*>(xb + t * 24);
    #pragma unroll
    for (int u = 0; u < 6; ++u) {
      float4 L = xb4[u];
      fl[4 * u] = L.x; fl[4 * u + 1] = L.y; fl[4 * u + 2] = L.z; fl[4 * u + 3] = L.w;
    }
    #pragma unroll
    for (int k = 0; k < 8; ++k) {
      px[k] = fl[3 * k]; py[k] = fl[3 * k + 1]; pz[k] = fl[3 * k + 2];
      dist[k] = 1e10f;
    }
  }
  float cx = xb[0], cy = xb[1], cz = xb[2];
  if (t == 0) { out_lds[0] = cx; out_lds[1] = cy; out_lds[2] = cz; }
  int lane = t & 63, wv = t >> 6;
  for (int it = 1; it < 128; ++it) {
    float bv = -1.f, bx = px[0], by = py[0], bz = pz[0];
    #pragma unroll
    for (int k = 0; k < 8; ++k) {
      float d = dist2_exact(px[k], py[k], pz[k], cx, cy, cz);
      float nd = fminf(dist[k], d);
      dist[k] = nd;
      bool up = nd > bv;               // strict > keeps smallest k (ascending idx)
      bv = up ? nd : bv;
      bx = up ? px[k] : bx; by = up ? py[k] : by; bz = up ? pz[k] : bz;
    }
    float wm = rl_f(wave_max64_dpp(bv), 63);
    unsigned long long m = __ballot(bv == wm);
    int src = __ffsll(m) - 1;          // smallest lane == smallest point index
    int pb = it & 1;
    if (lane == src) {
      candf[pb][wv][0] = bv; candf[pb][wv][1] = bx;
      candf[pb][wv][2] = by; candf[pb][wv][3] = bz;
    }
    __syncthreads();
    float4 c0 = *reinterpret_cast<const float4*>(&candf[pb][0][0]);
    float4 c1 = *reinterpret_cast<const float4*>(&candf[pb][1][0]);
    float4 c2 = *reinterpret_cast<const float4*>(&candf[pb][2][0]);
    float4 c3 = *reinterpret_cast<const float4*>(&candf[pb][3][0]);
    float4 c4 = *reinterpret_cast<const float4*>(&candf[pb][4][0]);
    float4 c5 = *reinterpret_cast<const float4*>(&candf[pb][5][0]);
    float4 c6 = *reinterpret_cast<const float4*>(&candf[pb][6][0]);
    float4 c7 = *reinterpret_cast<const float4*>(&candf[pb][7][0]);
    float4 a01 = cand_max(c0, c1), a23 = cand_max(c2, c3);
    float4 a45 = cand_max(c4, c5), a67 = cand_max(c6, c7);
    float4 a03 = cand_max(a01, a23), a47 = cand_max(a45, a67);
    float4 bc = cand_max(a03, a47);
    cx = bc.y; cy = bc.z; cz = bc.w;
    if (t == 0) { out_lds[it * 3] = cx; out_lds[it * 3 + 1] = cy; out_lds[it * 3 + 2] = cz; }
  }
  __syncthreads();
  for (int e = t; e < 384; e += 512) out[e] = out_lds[e];
}

// ---------------- FPS stage 2/3 bodies ----------------
__device__ __forceinline__ void fps2_body(const float* __restrict__ xyz1,
                                          float* __restrict__ out_xyz, int b, int t) {
  const float* xb = xyz1 + (size_t)b * 128 * 3;
  float* out = out_xyz + (size_t)b * 64 * 3;
  float px[2], py[2], pz[2], dist[2];
  #pragma unroll
  for (int k = 0; k < 2; ++k) {
    int i = t * 2 + k;
    px[k] = xb[i * 3]; py[k] = xb[i * 3 + 1]; pz[k] = xb[i * 3 + 2];
    dist[k] = 1e10f;
  }
  float cx = rl_f(px[0], 0), cy = rl_f(py[0], 0), cz = rl_f(pz[0], 0);
  if (t == 0) { out[0] = cx; out[1] = cy; out[2] = cz; }
  for (int it = 1; it < 64; ++it) {
    float bv = -1.f; int lidx = t * 2;
    #pragma unroll
    for (int k = 0; k < 2; ++k) {
      float d = dist2_exact(px[k], py[k], pz[k], cx, cy, cz);
      float nd = fminf(dist[k], d);
      dist[k] = nd;
      if (nd > bv) { bv = nd; lidx = t * 2 + k; }
    }
    float wm = rl_f(wave_max64_dpp(bv), 63);
    unsigned long long m = __ballot(bv == wm);
    int src = __ffsll(m) - 1;
    int widx = __builtin_amdgcn_readlane(lidx, src);
    int sl = widx >> 1, sk = widx & 1;
    float qx = sk ? px[1] : px[0], qy = sk ? py[1] : py[0], qz = sk ? pz[1] : pz[0];
    cx = rl_f(qx, sl); cy = rl_f(qy, sl); cz = rl_f(qz, sl);
    if (t == 0) { out[it * 3] = cx; out[it * 3 + 1] = cy; out[it * 3 + 2] = cz; }
  }
}

__device__ __forceinline__ void fps3_body(const float* __restrict__ xyz2,
                                          float* __restrict__ out_xyz, int b, int t) {
  const float* xb = xyz2 + (size_t)b * 64 * 3;
  float* out = out_xyz + (size_t)b * 32 * 3;
  float px = xb[t * 3], py = xb[t * 3 + 1], pz = xb[t * 3 + 2];
  float dist = 1e10f;
  float cx = rl_f(px, 0), cy = rl_f(py, 0), cz = rl_f(pz, 0);
  if (t == 0) { out[0] = cx; out[1] = cy; out[2] = cz; }
  for (int it = 1; it < 32; ++it) {
    float d = dist2_exact(px, py, pz, cx, cy, cz);
    dist = fminf(dist, d);
    float wm = rl_f(wave_max64_dpp(dist), 63);
    unsigned long long m = __ballot(dist == wm);
    int widx = __ffsll(m) - 1;
    cx = rl_f(px, widx); cy = rl_f(py, widx); cz = rl_f(pz, widx);
    if (t == 0) { out[it * 3] = cx; out[it * 3 + 1] = cy; out[it * 3 + 2] = cz; }
  }
}

// ---------------- ball query (single wave) ----------------
__device__ __forceinline__ int ball_query_wave(const float* __restrict__ xb, int N,
                                               float cx, float cy, float cz, float r2,
                                               int nsample, int* list, int lane) {
  int cnt = 0;
  for (int base = 0; base < N && cnt < nsample; base += 64) {
    int i = base + lane;
    float d2 = dist2_exact(xb[i * 3], xb[i * 3 + 1], xb[i * 3 + 2], cx, cy, cz);
    bool in = d2 < r2;
    unsigned long long m = __ballot(in);
    if (in) {
      int pos = cnt + __popcll(m & ((1ull << lane) - 1ull));
      if (pos < nsample) list[pos] = i;
    }
    cnt += __popcll(m);
  }
  return cnt;
}

// software-pipelined variant for large N.
__device__ __forceinline__ int ball_query_wave_pf(const float* __restrict__ xb, int N,
                                                  float cx, float cy, float cz, float r2,
                                                  int nsample, int* list, int lane) {
  int cnt = 0;
  float x = xb[lane * 3], y = xb[lane * 3 + 1], z = xb[lane * 3 + 2];
  for (int base = 0; base < N && cnt < nsample; base += 64) {
    float nx = x, ny = y, nz = z;
    if (base + 64 < N) {
      int ni = base + 64 + lane;
      nx = xb[ni * 3]; ny = xb[ni * 3 + 1]; nz = xb[ni * 3 + 2];
    }
    float d2 = dist2_exact(x, y, z, cx, cy, cz);
    bool in = d2 < r2;
    unsigned long long m = __ballot(in);
    if (in) {
      int pos = cnt + __popcll(m & ((1ull << lane) - 1ull));
      if (pos < nsample) list[pos] = base + lane;
    }
    cnt += __popcll(m);
    x = nx; y = ny; z = nz;
  }
  return cnt;
}

#define FMA4(aq, w0, w1, w2, w3, xv, comp)                                   \
  aq = fmaf(w0.comp, xv.x, fmaf(w1.comp, xv.y, fmaf(w2.comp, xv.z,           \
       fmaf(w3.comp, xv.w, aq))))

// ---------------- group1 (+fps2): 4 groups/block, 128 j, grid (33,64) --------
__global__ __launch_bounds__(256) void group1_fps2_kernel(const float* __restrict__ pc,
    const float* __restrict__ newxyz1, const float* __restrict__ wbuf,
    const float* __restrict__ bbuf, float* __restrict__ U1,
    float* __restrict__ xyz2) {
  int t = threadIdx.x;
  int b = blockIdx.y;
  if (blockIdx.x == 32) {
    if (t < 64) fps2_body(newxyz1, xyz2, b, t);
    return;
  }
  __shared__ float smA[1536];      // X [128][12]  /  pm1 [16][64] (aliased)
  __shared__ float h1[128 * 36];
  __shared__ float W0s[384];
  __shared__ float W1s[2048];
  __shared__ float F1[4 * 64];
  __shared__ float ctr[12];
  __shared__ int lst[128];         // [4][32]
  __shared__ int cnts[4];
  float* X = smA;
  float* pm1 = smA;
  int s0 = blockIdx.x * 4;
  const float* xb = pc + (size_t)b * 4096 * 3;
  const float* W2g = wbuf + 2432;
  for (int e = t; e < 384; e += 256) W0s[e] = wbuf[e];
  for (int e = t; e < 2048; e += 256) W1s[e] = wbuf[384 + e];
  int lane = t & 63, wv = t >> 6;
  {
    int g = wv;
    const float* c3 = newxyz1 + ((size_t)b * 128 + s0 + g) * 3;
    float cx = c3[0], cy = c3[1], cz = c3[2];
    if (lane == 0) { ctr[g * 3] = cx; ctr[g * 3 + 1] = cy; ctr[g * 3 + 2] = cz; }
    int cnt = ball_query_wave_pf(xb, 4096, cx, cy, cz, 4.0e-4f, 32, lst + g * 32, lane);
    if (lane == 0) cnts[g] = cnt;
  }
  __syncthreads();
  if (t < 128) { int g = t >> 5, q = t & 31; if (q >= cnts[g]) lst[t] = (cnts[g] > 0) ? lst[g * 32] : 0; }
  __syncthreads();
  if (t < 128) {
    int j = t;
    int g = j >> 5;
    int i = lst[g * 32 + (j & 31)];
    float px = xb[i * 3], py = xb[i * 3 + 1], pz = xb[i * 3 + 2];
    float4 v0, v1, v2;
    v0.x = px - ctr[g * 3]; v0.y = py - ctr[g * 3 + 1]; v0.z = pz - ctr[g * 3 + 2];
    v0.w = px; v1.x = py; v1.y = pz; v1.z = px; v1.w = py;
    v2.x = pz; v2.y = 0.f; v2.z = 0.f; v2.w = 0.f;
    *reinterpret_cast<float4*>(&X[j * 12 + 0]) = v0;
    *reinterpret_cast<float4*>(&X[j * 12 + 4]) = v1;
    *reinterpret_cast<float4*>(&X[j * 12 + 8]) = v2;
  }
  __syncthreads();
  {
    int o_l0 = t & 31, jb0 = (t >> 5) * 16;
    float w0v[12];
    #pragma unroll
    for (int c = 0; c < 12; ++c) w0v[c] = W0s[c * 32 + o_l0];
    float b0 = bbuf[o_l0];
    for (int jj = 0; jj < 16; ++jj) {
      int j = jb0 + jj;
      float4 x0 = *reinterpret_cast<const float4*>(&X[j * 12 + 0]);
      float4 x1 = *reinterpret_cast<const float4*>(&X[j * 12 + 4]);
      float4 x2 = *reinterpret_cast<const float4*>(&X[j * 12 + 8]);
      float a = b0;
      a = fmaf(w0v[0], x0.x, a); a = fmaf(w0v[1], x0.y, a);
      a = fmaf(w0v[2], x0.z, a); a = fmaf(w0v[3], x0.w, a);
      a = fmaf(w0v[4], x1.x, a); a = fmaf(w0v[5], x1.y, a);
      a = fmaf(w0v[6], x1.z, a); a = fmaf(w0v[7], x1.w, a);
      a = fmaf(w0v[8], x2.x, a); a = fmaf(w0v[9], x2.y, a);
      a = fmaf(w0v[10], x2.z, a); a = fmaf(w0v[11], x2.w, a);
      h1[j * 36 + o_l0] = fmaxf(a, 0.f);
    }
  }
  __syncthreads();
  {
    int ot1 = t & 15, jt1 = t >> 4;
    int o0 = ot1 * 4, j0 = jt1 * 8;
    float acc[8][4];
    #pragma unroll
    for (int q = 0; q < 8; ++q)
      #pragma unroll
      for (int r = 0; r < 4; ++r) acc[q][r] = bbuf[32 + o0 + r];
    for (int c4 = 0; c4 < 8; ++c4) {
      int c = c4 * 4;
      float4 w0 = *reinterpret_cast<const float4*>(&W1s[(c + 0) * 64 + o0]);
      float4 w1 = *reinterpret_cast<const float4*>(&W1s[(c + 1) * 64 + o0]);
      float4 w2 = *reinterpret_cast<const float4*>(&W1s[(c + 2) * 64 + o0]);
      float4 w3 = *reinterpret_cast<const float4*>(&W1s[(c + 3) * 64 + o0]);
      #pragma unroll
      for (int q = 0; q < 8; ++q) {
        float4 xv = *reinterpret_cast<const float4*>(&h1[(j0 + q) * 36 + c]);
        FMA4(acc[q][0], w0, w1, w2, w3, xv, x);
        FMA4(acc[q][1], w0, w1, w2, w3, xv, y);
        FMA4(acc[q][2], w0, w1, w2, w3, xv, z);
        FMA4(acc[q][3], w0, w1, w2, w3, xv, w);
      }
    }
    float m[4] = {-1e30f, -1e30f, -1e30f, -1e30f};
    #pragma unroll
    for (int q = 0; q < 8; ++q)
      #pragma unroll
      for (int r = 0; r < 4; ++r) m[r] = fmaxf(m[r], acc[q][r]);
    float4 mv; mv.x = m[0]; mv.y = m[1]; mv.z = m[2]; mv.w = m[3];
    *reinterpret_cast<float4*>(&pm1[jt1 * 64 + o0]) = mv;
  }
  __syncthreads();
  {
    int o = t & 63, g = t >> 6;
    float v = pm1[(4 * g + 0) * 64 + o];
    v = fmaxf(v, pm1[(4 * g + 1) * 64 + o]);
    v = fmaxf(v, pm1[(4 * g + 2) * 64 + o]);
    v = fmaxf(v, pm1[(4 * g + 3) * 64 + o]);
    F1[g * 64 + o] = fmaxf(v, 0.f);
  }
  __syncthreads();
  {
    int o = t & 127, ph = t >> 7;
    float a0 = bbuf[96 + o], a1 = a0;
    #pragma unroll 8
    for (int c = 0; c < 64; ++c) {
      float w = W2g[(3 + c) * 128 + o];
      a0 = fmaf(w, F1[ph * 64 + c], a0);
      a1 = fmaf(w, F1[(ph + 2) * 64 + c], a1);
    }
    U1[((size_t)b * 128 + s0 + ph) * 128 + o] = a0;
    U1[((size_t)b * 128 + s0 + ph + 2) * 128 + o] = a1;
  }
}

// ---------------- group2 (+fps3): 2 groups/block, 64 j, grid (33,64) ---------
__global__ __launch_bounds__(256) void group2_fps3_kernel(const float* __restrict__ xyz1,
    const float* __restrict__ newxyz2, const float* __restrict__ U1,
    const float* __restrict__ wbuf, const float* __restrict__ bbuf,
    float* __restrict__ U2, float* __restrict__ xyz3) {
  int t = threadIdx.x;
  int b = blockIdx.y;
  if (blockIdx.x == 32) {
    if (t < 64) fps3_body(newxyz2, xyz3, b, t);
    return;
  }
  __shared__ float Hs[64 * 132];   // front 1024 floats reused as pm [8][128]
  __shared__ float W2x[384];
  __shared__ float D[64 * 4];
  __shared__ float F2[2 * 128];
  __shared__ float ctr[6];
  __shared__ int lst[64];          // [2][32]
  __shared__ int cnts[2];
  float* pm = Hs;
  int s0 = blockIdx.x * 2;
  const float* xb = xyz1 + (size_t)b * 128 * 3;
  const float* W2g = wbuf + 2432;
  const float* W3g = wbuf + 11136;
  const float* W4g = wbuf + 27520;
  int lane = t & 63, wv = t >> 6;
  for (int e = t; e < 384; e += 256) W2x[e] = W2g[e];
  if (wv < 2) {
    int g = wv;
    const float* c3 = newxyz2 + ((size_t)b * 64 + s0 + g) * 3;
    float cx = c3[0], cy = c3[1], cz = c3[2];
    if (lane == 0) { ctr[g * 3] = cx; ctr[g * 3 + 1] = cy; ctr[g * 3 + 2] = cz; }
    int cnt = ball_query_wave(xb, 128, cx, cy, cz, 1.6e-3f, 32, lst + g * 32, lane);
    if (lane == 0) cnts[g] = cnt;
  }
  __syncthreads();
  if (t < 64) { int g = t >> 5, q = t & 31; if (q >= cnts[g]) lst[t] = (cnts[g] > 0) ? lst[g * 32] : 0; }
  __syncthreads();
  int ot = t & 31, jt = t >> 5;
  int o0 = ot * 4, j0 = jt * 8;
  float4 wx0 = *reinterpret_cast<const float4*>(&W2x[0 * 128 + o0]);
  float4 wx1 = *reinterpret_cast<const float4*>(&W2x[1 * 128 + o0]);
  float4 wx2 = *reinterpret_cast<const float4*>(&W2x[2 * 128 + o0]);
  if (t < 64) {
    int j = t;
    int g = j >> 5;
    int i = lst[g * 32 + (j & 31)];
    D[j * 4 + 0] = xb[i * 3 + 0] - ctr[g * 3 + 0];
    D[j * 4 + 1] = xb[i * 3 + 1] - ctr[g * 3 + 1];
    D[j * 4 + 2] = xb[i * 3 + 2] - ctr[g * 3 + 2];
    D[j * 4 + 3] = 0.f;
  }
  __syncthreads();
  #pragma unroll
  for (int q = 0; q < 8; ++q) {
    int j = j0 + q;
    int g = j >> 5;
    int i = lst[g * 32 + (j & 31)];
    float4 u = *reinterpret_cast<const float4*>(&U1[((size_t)b * 128 + i) * 128 + o0]);
    float dx = D[j * 4], dy = D[j * 4 + 1], dz = D[j * 4 + 2];
    float4 h;
    h.x = fmaf(wx0.x, dx, fmaf(wx1.x, dy, fmaf(wx2.x, dz, u.x)));
    h.y = fmaf(wx0.y, dx, fmaf(wx1.y, dy, fmaf(wx2.y, dz, u.y)));
    h.z = fmaf(wx0.z, dx, fmaf(wx1.z, dy, fmaf(wx2.z, dz, u.z)));
    h.w = fmaf(wx0.w, dx, fmaf(wx1.w, dy, fmaf(wx2.w, dz, u.w)));
    h.x = fmaxf(h.x, 0.f); h.y = fmaxf(h.y, 0.f);
    h.z = fmaxf(h.z, 0.f); h.w = fmaxf(h.w, 0.f);
    *reinterpret_cast<float4*>(&Hs[j * 132 + o0]) = h;
  }
  __syncthreads();
  float acc[8][4];
  #pragma unroll
  for (int q = 0; q < 8; ++q)
    #pragma unroll
    for (int r = 0; r < 4; ++r) acc[q][r] = bbuf[224 + o0 + r];
  for (int c4 = 0; c4 < 32; ++c4) {
    int c = c4 * 4;
    float4 w0 = *reinterpret_cast<const float4*>(&W3g[(c + 0) * 128 + o0]);
    float4 w1 = *reinterpret_cast<const float4*>(&W3g[(c + 1) * 128 + o0]);
    float4 w2 = *reinterpret_cast<const float4*>(&W3g[(c + 2) * 128 + o0]);
    float4 w3 = *reinterpret_cast<const float4*>(&W3g[(c + 3) * 128 + o0]);
    #pragma unroll
    for (int q = 0; q < 8; ++q) {
      float4 xv = *reinterpret_cast<const float4*>(&Hs[(j0 + q) * 132 + c]);
      FMA4(acc[q][0], w0, w1, w2, w3, xv, x);
      FMA4(acc[q][1], w0, w1, w2, w3, xv, y);
      FMA4(acc[q][2], w0, w1, w2, w3, xv, z);
      FMA4(acc[q][3], w0, w1, w2, w3, xv, w);
    }
  }
  __syncthreads();
  {
    float m[4] = {-1e30f, -1e30f, -1e30f, -1e30f};
    #pragma unroll
    for (int q = 0; q < 8; ++q)
      #pragma unroll
      for (int r = 0; r < 4; ++r) m[r] = fmaxf(m[r], acc[q][r]);
    float4 mv; mv.x = m[0]; mv.y = m[1]; mv.z = m[2]; mv.w = m[3];
    *reinterpret_cast<float4*>(&pm[jt * 128 + o0]) = mv;
  }
  __syncthreads();
  {
    int o = t & 127, g = t >> 7;
    float v = pm[(g * 4 + 0) * 128 + o];
    v = fmaxf(v, pm[(g * 4 + 1) * 128 + o]);
    v = fmaxf(v, pm[(g * 4 + 2) * 128 + o]);
    v = fmaxf(v, pm[(g * 4 + 3) * 128 + o]);
    F2[g * 128 + o] = fmaxf(v, 0.f);
  }
  __syncthreads();
  {
    int o = t;
    float a0 = bbuf[352 + o], a1 = a0;
    #pragma unroll 4
    for (int c = 0; c < 128; ++c) {
      float w = W4g[(3 + c) * 256 + o];
      a0 = fmaf(w, F2[c], a0);
      a1 = fmaf(w, F2[128 + c], a1);
    }
    U2[((size_t)b * 64 + s0) * 256 + o] = a0;
    U2[((size_t)b * 64 + s0 + 1) * 256 + o] = a1;
  }
}

// ---------------- group3: 2 groups/block, 32 j, grid (16,64) -----------------
__global__ __launch_bounds__(256) void group3_kernel(const float* __restrict__ xyz2,
    const float* __restrict__ newxyz3, const float* __restrict__ U2,
    const float* __restrict__ wbuf, const float* __restrict__ bbuf,
    float* __restrict__ out) {
  __shared__ float Hs3[32 * 260];  // front 1024 floats reused as pm3 [4][256]
  __shared__ float W4x[768];
  __shared__ float D[32 * 4];
  __shared__ float ctr[6];
  __shared__ int lst[32];          // [2][16]
  __shared__ int cnts[2];
  float* pm3 = Hs3;
  int t = threadIdx.x;
  int b = blockIdx.y, s0 = blockIdx.x * 2;
  const float* xb = xyz2 + (size_t)b * 64 * 3;
  const float* W4g = wbuf + 27520;
  const float* W5g = wbuf + 61312;
  int lane = t & 63, wv = t >> 6;
  for (int e = t; e < 768; e += 256) W4x[e] = W4g[e];
  if (wv < 2) {
    int g = wv;
    const float* c3 = newxyz3 + ((size_t)b * 32 + s0 + g) * 3;
    float cx = c3[0], cy = c3[1], cz = c3[2];
    if (lane == 0) { ctr[g * 3] = cx; ctr[g * 3 + 1] = cy; ctr[g * 3 + 2] = cz; }
    int cnt = ball_query_wave(xb, 64, cx, cy, cz, 6.4e-3f, 16, lst + g * 16, lane);
    if (lane == 0) cnts[g] = cnt;
  }
  __syncthreads();
  if (t < 32) { int g = t >> 4, q = t & 15; if (q >= cnts[g]) lst[t] = (cnts[g] > 0) ? lst[g * 16] : 0; }
  __syncthreads();
  int ot = t & 63, jt = t >> 6;
  int o0 = ot * 4, j0 = jt * 8;
  float4 wx0 = *reinterpret_cast<const float4*>(&W4x[0 * 256 + o0]);
  float4 wx1 = *reinterpret_cast<const float4*>(&W4x[1 * 256 + o0]);
  float4 wx2 = *reinterpret_cast<const float4*>(&W4x[2 * 256 + o0]);
  if (t < 32) {
    int j = t;
    int g = j >> 4;
    int i = lst[g * 16 + (j & 15)];
    D[j * 4 + 0] = xb[i * 3 + 0] - ctr[g * 3 + 0];
    D[j * 4 + 1] = xb[i * 3 + 1] - ctr[g * 3 + 1];
    D[j * 4 + 2] = xb[i * 3 + 2] - ctr[g * 3 + 2];
    D[j * 4 + 3] = 0.f;
  }
  __syncthreads();
  #pragma unroll
  for (int q = 0; q < 8; ++q) {
    int j = j0 + q;
    int g = j >> 4;
    int i = lst[g * 16 + (j & 15)];
    float4 u = *reinterpret_cast<const float4*>(&U2[((size_t)b * 64 + i) * 256 + o0]);
    float dx = D[j * 4], dy = D[j * 4 + 1], dz = D[j * 4 + 2];
    float4 h;
    h.x = fmaf(wx0.x, dx, fmaf(wx1.x, dy, fmaf(wx2.x, dz, u.x)));
    h.y = fmaf(wx0.y, dx, fmaf(wx1.y, dy, fmaf(wx2.y, dz, u.y)));
    h.z = fmaf(wx0.z, dx, fmaf(wx1.z, dy, fmaf(wx2.z, dz, u.z)));
    h.w = fmaf(wx0.w, dx, fmaf(wx1.w, dy, fmaf(wx2.w, dz, u.w)));
    h.x = fmaxf(h.x, 0.f); h.y = fmaxf(h.y, 0.f);
    h.z = fmaxf(h.z, 0.f); h.w = fmaxf(h.w, 0.f);
    *reinterpret_cast<float4*>(&Hs3[j * 260 + o0]) = h;
  }
  __syncthreads();
  float acc[8][4];
  #pragma unroll
  for (int q = 0; q < 8; ++q)
    #pragma unroll
    for (int r = 0; r < 4; ++r) acc[q][r] = bbuf[608 + o0 + r];
  for (int c4 = 0; c4 < 64; ++c4) {
    int c = c4 * 4;
    float4 w0 = *reinterpret_cast<const float4*>(&W5g[(c + 0) * 256 + o0]);
    float4 w1 = *reinterpret_cast<const float4*>(&W5g[(c + 1) * 256 + o0]);
    float4 w2 = *reinterpret_cast<const float4*>(&W5g[(c + 2) * 256 + o0]);
    float4 w3 = *reinterpret_cast<const float4*>(&W5g[(c + 3) * 256 + o0]);
    #pragma unroll
    for (int q = 0; q < 8; ++q) {
      float4 xv = *reinterpret_cast<const float4*>(&Hs3[(j0 + q) * 260 + c]);
      FMA4(acc[q][0], w0, w1, w2, w3, xv, x);
      FMA4(acc[q][1], w0, w1, w2, w3, xv, y);
      FMA4(acc[q][2], w0, w1, w2, w3, xv, z);
      FMA4(acc[q][3], w0, w1, w2, w3, xv, w);
    }
  }
  __syncthreads();
  {
    float m[4] = {-1e30f, -1e30f, -1e30f, -1e30f};
    #pragma unroll
    for (int q = 0; q < 8; ++q)
      #pragma unroll
      for (int r = 0; r < 4; ++r) m[r] = fmaxf(m[r], acc[q][r]);
    float4 mv; mv.x = m[0]; mv.y = m[1]; mv.z = m[2]; mv.w = m[3];
    *reinterpret_cast<float4*>(&pm3[jt * 256 + o0]) = mv;
  }
  __syncthreads();
  {
    int o = t;
    #pragma unroll
    for (int g = 0; g < 2; ++g) {
      float v = fmaxf(pm3[(g * 2 + 0) * 256 + o], pm3[(g * 2 + 1) * 256 + o]);
      out[((size_t)b * 256 + o) * 32 + s0 + g] = fmaxf(v, 0.f);
    }
  }
}

extern "C" void kernel_launch(void* const* d_in, const int* in_sizes, int n_in,
                              void* d_out, int out_size, void* d_ws, size_t ws_size,
                              hipStream_t stream) {
  (void)in_sizes; (void)n_in; (void)out_size; (void)ws_size;
  const float* pc = (const float*)d_in[0];
  PrepArgs pa;
  for (int l = 0; l < 6; ++l) {
    pa.w[l]  = (const float*)d_in[1 + 5 * l + 0];
    pa.g[l]  = (const float*)d_in[1 + 5 * l + 1];
    pa.be[l] = (const float*)d_in[1 + 5 * l + 2];
    pa.rm[l] = (const float*)d_in[1 + 5 * l + 3];
    pa.rv[l] = (const float*)d_in[1 + 5 * l + 4];
  }
  float* ws = (float*)d_ws;
  float* wbuf = ws + 0;
  float* bbuf = ws + 126848;
  float* xyz1 = ws + 131072;
  float* xyz2 = ws + 155648;
  float* xyz3 = ws + 167936;
  float* U1   = ws + 174080;    // 64*128*128 floats
  float* U2   = ws + 1222656;   // 64*64*256 floats
  float* out  = (float*)d_out;

  fps1_prep_kernel<<<314, 512, 0, stream>>>(pc, xyz1, pa, wbuf, bbuf);
  group1_fps2_kernel<<<dim3(33, 64), 256, 0, stream>>>(pc, xyz1, wbuf, bbuf, U1, xyz2);
  group2_fps3_kernel<<<dim3(33, 64), 256, 0, stream>>>(xyz1, xyz2, U1, wbuf, bbuf, U2, xyz3);
  group3_kernel<<<dim3(16, 64), 256, 0, stream>>>(xyz2, xyz3, U2, wbuf, bbuf, out);
}